// Round 6
// baseline (626.224 us; speedup 1.0000x reference)
//
#include <hip/hip_runtime.h>

#define BTOT   131072
#define INDIM  128
#define OUTDIM 512
#define VBS    128
#define NCHUNK (BTOT / VBS)   // 1024
#define MAXIT  16
#define TTOL   1e-4f
#define EPS    1e-5f
#define TSTR   520            // tile row stride in halves (8 halves pad)

typedef _Float16 half8  __attribute__((ext_vector_type(8)));
typedef float    floatx4 __attribute__((ext_vector_type(4)));

// ---------------------------------------------------------------------------
// DPP wave64 reductions (VALU-only, no LDS/DS traffic). dpp_ctrl must be an
// immediate -> template parameter.
// row_shr:1/2/4/8 accumulate within each row-of-16 (lanes 15/31/47/63 hold row
// totals), row_bcast:15 + row_bcast:31 fold rows; lane 63 has the wave total.
// ---------------------------------------------------------------------------
template <int CTRL>
__device__ __forceinline__ float dpp_add_step(float x) {
    int t = __builtin_amdgcn_update_dpp(0, __builtin_bit_cast(int, x),
                                        CTRL, 0xF, 0xF, true);
    return x + __builtin_bit_cast(float, t);
}
__device__ __forceinline__ float wave_sum_bcast(float x) {
    x = dpp_add_step<0x111>(x);   // row_shr:1
    x = dpp_add_step<0x112>(x);   // row_shr:2
    x = dpp_add_step<0x114>(x);   // row_shr:4
    x = dpp_add_step<0x118>(x);   // row_shr:8
    x = dpp_add_step<0x142>(x);   // row_bcast:15
    x = dpp_add_step<0x143>(x);   // row_bcast:31
    return __builtin_bit_cast(float,
        __builtin_amdgcn_readlane(__builtin_bit_cast(int, x), 63));
}
template <int CTRL>
__device__ __forceinline__ float dpp_max_step(float x) {
    int xi = __builtin_bit_cast(int, x);
    int t = __builtin_amdgcn_update_dpp(xi, xi, CTRL, 0xF, 0xF, false);
    return fmaxf(x, __builtin_bit_cast(float, t));
}
__device__ __forceinline__ float wave_max_bcast(float x) {
    x = dpp_max_step<0x111>(x);
    x = dpp_max_step<0x112>(x);
    x = dpp_max_step<0x114>(x);
    x = dpp_max_step<0x118>(x);
    x = dpp_max_step<0x142>(x);
    x = dpp_max_step<0x143>(x);
    return __builtin_bit_cast(float,
        __builtin_amdgcn_readlane(__builtin_bit_cast(int, x), 63));
}

// ---------------------------------------------------------------------------
// Kernel 0: convert W [512x128] fp32 -> fp16 into workspace (row-major [o][k])
// ---------------------------------------------------------------------------
__global__ void w_to_half_kernel(const float* __restrict__ W,
                                 _Float16* __restrict__ Wh) {
    int i = blockIdx.x * blockDim.x + threadIdx.x;   // float4 index, 0..16383
    const float4 v = ((const float4*)W)[i];
    union { _Float16 h[4]; uint2 u; } p;
    p.h[0] = (_Float16)v.x; p.h[1] = (_Float16)v.y;
    p.h[2] = (_Float16)v.z; p.h[3] = (_Float16)v.w;
    ((uint2*)Wh)[i] = p.u;
}

// ---------------------------------------------------------------------------
// Fully fused: GEMM(fp16 MFMA) + GhostBN + priors + sparsemax, one block per
// virtual batch of 128 rows. 1024 threads = 16 waves.
// Phase 1-3 as R4 (GEMM -> stats -> normalized fp16 tile in LDS).
// Phase 4: wave w owns rows w*8..w*8+7; bulk load into x[8][8] regs, DPP
// reductions (no DS), joint Michelot over 8 rows, coalesced stores.
// ---------------------------------------------------------------------------
__global__ void __launch_bounds__(1024)
fused_all(const float* __restrict__ priors,
          const float* __restrict__ feat,
          const _Float16* __restrict__ Wh,
          const float* __restrict__ gamma,
          const float* __restrict__ beta,
          float* __restrict__ out)
{
    __shared__ __align__(16) _Float16 tile[VBS][TSTR];   // 133120 B
    __shared__ float lds_ab[2][OUTDIM];                  // 4096 B
    // stats overlay the tile region: consumed (phase 2) before tile writes
    float* lds_sum = (float*)&tile[0][0];                // [8][512]
    float* lds_sq  = lds_sum + 8 * OUTDIM;               // [8][512]

    const int tid   = threadIdx.x;
    const int w     = tid >> 6;      // wave 0..15
    const int lane  = tid & 63;
    const int i16   = lane & 15;
    const int quad  = lane >> 4;     // 0..3
    const int w8    = w & 7;         // row group 0..7
    const int ch    = w >> 3;        // col half 0..1
    const int chunk = blockIdx.x;
    const int row0  = chunk * VBS + w8 * 16;
    const int cb0   = ch * 256;

    // ---- A fragments: A[m=lane&15][k=quad*8+j] per 32-wide k-tile ----
    half8 afrag[4];
    {
        const float* ap = feat + (size_t)(row0 + i16) * INDIM + quad * 8;
        #pragma unroll
        for (int kt = 0; kt < 4; ++kt) {
            float4 v0 = *(const float4*)(ap + kt * 32);
            float4 v1 = *(const float4*)(ap + kt * 32 + 4);
            half8 h;
            h[0]=(_Float16)v0.x; h[1]=(_Float16)v0.y; h[2]=(_Float16)v0.z; h[3]=(_Float16)v0.w;
            h[4]=(_Float16)v1.x; h[5]=(_Float16)v1.y; h[6]=(_Float16)v1.z; h[7]=(_Float16)v1.w;
            afrag[kt] = h;
        }
    }

    // ---- Phase 1: GEMM (16 col-tiles) + per-column partial stats (fp32) ----
    floatx4 acc[16];
    {
        const half8* wp0 = (const half8*)(Wh + (size_t)(cb0 + i16) * INDIM + quad * 8);
        #pragma unroll
        for (int t = 0; t < 16; ++t) {
            floatx4 c = {0.f, 0.f, 0.f, 0.f};
            #pragma unroll
            for (int kt = 0; kt < 4; ++kt) {
                half8 b = wp0[t * 256 + kt * 4];
                c = __builtin_amdgcn_mfma_f32_16x16x32_f16(afrag[kt], b, c, 0, 0, 0);
            }
            acc[t] = c;
            float s = c.x + c.y + c.z + c.w;
            float q = c.x*c.x + c.y*c.y + c.z*c.z + c.w*c.w;
            s += __shfl_xor(s, 16); q += __shfl_xor(q, 16);
            s += __shfl_xor(s, 32); q += __shfl_xor(q, 32);
            if (quad == 0) {
                lds_sum[w8 * OUTDIM + cb0 + t * 16 + i16] = s;
                lds_sq [w8 * OUTDIM + cb0 + t * 16 + i16] = q;
            }
        }
    }
    __syncthreads();

    // ---- Phase 2: reduce stats across 8 row-groups -> BN affine a,b ----
    if (tid < OUTDIM) {
        float s = 0.f, q = 0.f;
        #pragma unroll
        for (int j = 0; j < 8; ++j) {
            s += lds_sum[j * OUTDIM + tid];
            q += lds_sq [j * OUTDIM + tid];
        }
        float mean = s * (1.0f / VBS);
        float var  = q * (1.0f / VBS) - mean * mean;
        float rstd = 1.0f / sqrtf(var + EPS);
        float a = gamma[tid] * rstd;
        float b = beta[tid] - mean * a;
        lds_ab[0][tid] = a;
        lds_ab[1][tid] = b;
    }
    __syncthreads();

    // ---- Phase 3: normalize acc, pack fp16 into LDS tile (clobbers stats) ----
    {
        const int r0 = w8 * 16 + quad * 4;
        #pragma unroll
        for (int t = 0; t < 16; ++t) {
            const int c = cb0 + t * 16 + i16;
            const float a = lds_ab[0][c];
            const float b = lds_ab[1][c];
            floatx4 v = acc[t];
            tile[r0 + 0][c] = (_Float16)fmaf(v.x, a, b);
            tile[r0 + 1][c] = (_Float16)fmaf(v.y, a, b);
            tile[r0 + 2][c] = (_Float16)fmaf(v.z, a, b);
            tile[r0 + 3][c] = (_Float16)fmaf(v.w, a, b);
        }
    }
    __syncthreads();

    // ---- Phase 4a: bulk load 8 rows into regs, apply priors, row maxes ----
    const int rbase = w * 8;
    float x[8][8];
    float tau[8];
    #pragma unroll
    for (int rr = 0; rr < 8; ++rr) {
        const int r = rbase + rr;
        const size_t grow = (size_t)(chunk * VBS + r) * OUTDIM + lane * 8;
        half8 h = *(const half8*)&tile[r][lane * 8];       // b128, conflict-free
        float4 p0 = *(const float4*)(priors + grow);       // coalesced 32 B/lane
        float4 p1 = *(const float4*)(priors + grow + 4);
        x[rr][0] = (float)h[0] * p0.x; x[rr][1] = (float)h[1] * p0.y;
        x[rr][2] = (float)h[2] * p0.z; x[rr][3] = (float)h[3] * p0.w;
        x[rr][4] = (float)h[4] * p1.x; x[rr][5] = (float)h[5] * p1.y;
        x[rr][6] = (float)h[6] * p1.z; x[rr][7] = (float)h[7] * p1.w;
        float m = fmaxf(fmaxf(fmaxf(x[rr][0], x[rr][1]), fmaxf(x[rr][2], x[rr][3])),
                        fmaxf(fmaxf(x[rr][4], x[rr][5]), fmaxf(x[rr][6], x[rr][7])));
        tau[rr] = wave_max_bcast(m) - 1.0f;   // tau0 = max-1 (valid superset)
    }

    // ---- Phase 4b: joint Michelot over 8 rows, DPP reductions, early exit ----
    // tau' = tau + (sum relu(x - tau) - 1) / count(x > tau); all wave-uniform.
    #pragma unroll 1
    for (int it = 0; it < MAXIT; ++it) {
        bool any = false;
        #pragma unroll
        for (int rr = 0; rr < 8; ++rr) {
            float s = 0.f, k = 0.f;
            #pragma unroll
            for (int j = 0; j < 8; ++j) {
                float d = x[rr][j] - tau[rr];
                s += fmaxf(d, 0.f);
                k += (d > 0.f) ? 1.f : 0.f;
            }
            s = wave_sum_bcast(s);
            k = wave_sum_bcast(k);
            float nt = tau[rr] + (s - 1.0f) * __builtin_amdgcn_rcpf(k);
            any |= (fabsf(nt - tau[rr]) > TTOL);
            tau[rr] = nt;
        }
        if (!any) break;   // wave-uniform (all taus from readlane)
    }

    // ---- Phase 4c: coalesced stores: relu(x - tau) ----
    #pragma unroll
    for (int rr = 0; rr < 8; ++rr) {
        const int r = rbase + rr;
        const size_t grow = (size_t)(chunk * VBS + r) * OUTDIM + lane * 8;
        float4 o0, o1;
        o0.x = fmaxf(x[rr][0] - tau[rr], 0.f); o0.y = fmaxf(x[rr][1] - tau[rr], 0.f);
        o0.z = fmaxf(x[rr][2] - tau[rr], 0.f); o0.w = fmaxf(x[rr][3] - tau[rr], 0.f);
        o1.x = fmaxf(x[rr][4] - tau[rr], 0.f); o1.y = fmaxf(x[rr][5] - tau[rr], 0.f);
        o1.z = fmaxf(x[rr][6] - tau[rr], 0.f); o1.w = fmaxf(x[rr][7] - tau[rr], 0.f);
        *(float4*)(out + grow)     = o0;
        *(float4*)(out + grow + 4) = o1;
    }
}

// ---------------------------------------------------------------------------
extern "C" void kernel_launch(void* const* d_in, const int* in_sizes, int n_in,
                              void* d_out, int out_size, void* d_ws, size_t ws_size,
                              hipStream_t stream) {
    const float* priors = (const float*)d_in[0];
    const float* feat   = (const float*)d_in[1];
    const float* W      = (const float*)d_in[2];
    const float* gamma  = (const float*)d_in[3];
    const float* beta   = (const float*)d_in[4];
    float* out = (float*)d_out;
    _Float16* Wh = (_Float16*)d_ws;   // 512*128*2 = 128 KB, only ws use

    hipLaunchKernelGGL(w_to_half_kernel, dim3(64), dim3(256), 0, stream, W, Wh);
    hipLaunchKernelGGL(fused_all, dim3(NCHUNK), dim3(1024), 0, stream,
                       priors, feat, Wh, gamma, beta, out);
}